// Round 13
// baseline (591.216 us; speedup 1.0000x reference)
//
#include <hip/hip_runtime.h>
#include <stdint.h>

#define B_ 8
#define T_ 2048
#define C_ 1024
#define E_ 8
#define K_ 2
#define CAP_ 320
#define DFF_ 4096
#define S_ (T_*K_)
#define NTOK (B_*T_)
#define ROWS_PER_E (B_*CAP_) // 2560

typedef __attribute__((ext_vector_type(8))) short short8;
typedef __attribute__((ext_vector_type(4))) float floatx4;

__device__ __forceinline__ unsigned short f2bf(float f) {
  union { float f; unsigned u; } v; v.f = f;
  unsigned r = v.u + 0x7fffu + ((v.u >> 16) & 1u);
  return (unsigned short)(r >> 16);
}
__device__ __forceinline__ float bf2f(unsigned short h) {
  union { unsigned u; float f; } v; v.u = ((unsigned)h) << 16;
  return v.f;
}

#define GLOAD16(g, l) __builtin_amdgcn_global_load_lds( \
    (const __attribute__((address_space(1))) void*)(g), \
    (__attribute__((address_space(3))) void*)(l), 16, 0, 0)

#define BARRIER() asm volatile("s_barrier" ::: "memory")
#define SCHEDB() __builtin_amdgcn_sched_barrier(0)

// ---------------- Router: fp64 logits, softmax, top-2 ----------------
__global__ void router_kernel(const float* __restrict__ x, const float* __restrict__ Wg,
                              const float* __restrict__ bg,
                              int* __restrict__ topk_e, float* __restrict__ topk_p)
{
  int token = (int)((blockIdx.x * blockDim.x + threadIdx.x) >> 6);
  int lane = threadIdx.x & 63;
  if (token >= NTOK) return;
  const float* xr = x + (size_t)token * C_;
  double acc[E_];
  #pragma unroll
  for (int e = 0; e < E_; ++e) acc[e] = 0.0;
  for (int c = lane*4; c < C_; c += 256) {
    float4 xv4 = *(const float4*)(xr + c);
    #pragma unroll
    for (int q = 0; q < 4; ++q) {
      double xv = (double)(q == 0 ? xv4.x : q == 1 ? xv4.y : q == 2 ? xv4.z : xv4.w);
      const float4* w4 = (const float4*)(Wg + (size_t)(c + q) * E_);
      float4 wa = w4[0], wb = w4[1];
      acc[0] += xv * (double)wa.x; acc[1] += xv * (double)wa.y;
      acc[2] += xv * (double)wa.z; acc[3] += xv * (double)wa.w;
      acc[4] += xv * (double)wb.x; acc[5] += xv * (double)wb.y;
      acc[6] += xv * (double)wb.z; acc[7] += xv * (double)wb.w;
    }
  }
  #pragma unroll
  for (int off = 32; off; off >>= 1) {
    #pragma unroll
    for (int e = 0; e < E_; ++e) acc[e] += __shfl_down(acc[e], off, 64);
  }
  if (lane == 0) {
    double lg[E_];
    double mx = -1e300;
    #pragma unroll
    for (int e = 0; e < E_; ++e) { lg[e] = acc[e] + (double)bg[e]; mx = fmax(mx, lg[e]); }
    double se = 0.0, pr[E_];
    #pragma unroll
    for (int e = 0; e < E_; ++e) { pr[e] = exp(lg[e] - mx); se += pr[e]; }
    #pragma unroll
    for (int e = 0; e < E_; ++e) pr[e] /= se;
    int e0 = 0;
    #pragma unroll
    for (int e = 1; e < E_; ++e) if (pr[e] > pr[e0]) e0 = e;
    int e1 = -1;
    #pragma unroll
    for (int e = 0; e < E_; ++e) {
      if (e == e0) continue;
      if (e1 < 0 || pr[e] > pr[e1]) e1 = e;
    }
    topk_e[token*2+0] = e0; topk_p[token*2+0] = (float)pr[e0];
    topk_e[token*2+1] = e1; topk_p[token*2+1] = (float)pr[e1];
  }
}

// ---------------- Scan: parallel Hillis-Steele prefix over 256 threads ----------------
__global__ void scan_kernel(const int* __restrict__ topk_e,
                            int* __restrict__ pos_arr, int* __restrict__ slot_src,
                            int* __restrict__ counts)
{
  const int b = blockIdx.x;
  const int tid = threadIdx.x;
  const int PT = S_ / 256; // 16
  __shared__ int cnt[256][E_ + 1];   // +1 pad: bank spread
  int e_loc[16];
  int local[E_];
  #pragma unroll
  for (int e = 0; e < E_; ++e) local[e] = 0;
  const int* te = topk_e + (size_t)b * S_;
  for (int j = 0; j < PT; ++j) {
    int e = te[tid*PT + j];
    e_loc[j] = e;
    local[e]++;
  }
  #pragma unroll
  for (int e = 0; e < E_; ++e) cnt[tid][e] = local[e];
  __syncthreads();
  // inclusive prefix over tid (8 steps)
  #pragma unroll
  for (int off = 1; off < 256; off <<= 1) {
    int v[E_];
    const bool act = (tid >= off);
    if (act) {
      #pragma unroll
      for (int e = 0; e < E_; ++e) v[e] = cnt[tid - off][e];
    }
    __syncthreads();
    if (act) {
      #pragma unroll
      for (int e = 0; e < E_; ++e) cnt[tid][e] += v[e];
    }
    __syncthreads();
  }
  if (tid == 255) {
    #pragma unroll
    for (int e = 0; e < E_; ++e) counts[e*B_ + b] = cnt[255][e];
  }
  int base[E_];
  #pragma unroll
  for (int e = 0; e < E_; ++e) base[e] = cnt[tid][e] - local[e];  // exclusive
  for (int j = 0; j < PT; ++j) {
    int e = e_loc[j];
    int p = base[e]++;
    int s = tid*PT + j;
    if (p < CAP_) {
      pos_arr[(size_t)b*S_ + s] = p;
      slot_src[((size_t)e*B_ + b)*CAP_ + p] = s >> 1;
    } else {
      pos_arr[(size_t)b*S_ + s] = -1;
    }
  }
}

// ---------------- Transpose + fp32->bf16 ----------------
__global__ void transpose_conv_kernel(const float* __restrict__ in, unsigned short* __restrict__ out,
                                      int R, int Cc)
{
  __shared__ float tile[64][33];
  const int e = blockIdx.z;
  const float* ine = in + (size_t)e * R * Cc;
  unsigned short* oute = out + (size_t)e * R * Cc;
  const int c0 = blockIdx.x * 32, r0 = blockIdx.y * 64;
  const int tx = threadIdx.x & 7, ty = threadIdx.x >> 3;
  #pragma unroll
  for (int p = 0; p < 2; ++p) {
    const int rr = p*32 + ty;
    float4 v = *(const float4*)(ine + (size_t)(r0 + rr) * Cc + c0 + tx*4);
    tile[rr][tx*4+0] = v.x; tile[rr][tx*4+1] = v.y;
    tile[rr][tx*4+2] = v.z; tile[rr][tx*4+3] = v.w;
  }
  __syncthreads();
  short8 s;
  #pragma unroll
  for (int j = 0; j < 8; ++j) s[j] = (short)f2bf(tile[tx*8+j][ty]);
  *(short8*)(oute + (size_t)(c0 + ty) * R + r0 + tx*8) = s;
}

// ---------------- Dispatch ----------------
__global__ void dispatch_kernel(const float* __restrict__ x, const int* __restrict__ slot_src,
                                const int* __restrict__ counts, unsigned short* __restrict__ Xd,
                                int e_base, int nexp)
{
  int row = (int)((blockIdx.x * blockDim.x + threadIdx.x) >> 6);
  int lane = threadIdx.x & 63;
  int total = nexp * B_ * CAP_;
  if (row >= total) return;
  int el = row / (B_*CAP_);
  int rem = row - el*(B_*CAP_);
  int b = rem / CAP_, slot = rem - b*CAP_;
  int eg = e_base + el;
  int cnt = counts[eg*B_ + b]; if (cnt > CAP_) cnt = CAP_;
  unsigned short* orow = Xd + (size_t)row * C_;
  if (slot < cnt) {
    int t = slot_src[((size_t)eg*B_ + b)*CAP_ + slot];
    const float4* xr = (const float4*)(x + ((size_t)b*T_ + t)*C_);
    #pragma unroll
    for (int i = 0; i < C_/256; ++i) {
      float4 v = xr[i*64 + lane];
      ushort4 o;
      o.x = f2bf(v.x); o.y = f2bf(v.y); o.z = f2bf(v.z); o.w = f2bf(v.w);
      ((ushort4*)orow)[i*64 + lane] = o;
    }
  } else {
    ushort4 z; z.x = z.y = z.z = z.w = 0;
    #pragma unroll
    for (int i = 0; i < C_/256; ++i) ((ushort4*)orow)[i*64 + lane] = z;
  }
}

// ---------------- GEMM 256x256, BK=64, mod-5 half-ring, ONE barrier/tile ----------------
// (K-loop identical to r12 — schedule proven; this round only changes the epilogue.)
// Epilogue: per-wave LDS scratch (16x64 bf16, row stride 72 shorts for bank spread);
// stage bias+relu'd values, read back short8 pairs, store 128B-contiguous rows as
// dwordx4 (16 stores/lane vs 128 scalar ushort). BARRIER() before scratch reuse;
// DMA is drained (no stages issued in last two tiles; vmcnt(0) at t+2==nk boundary).
template<int RELU>
__global__ __launch_bounds__(512) void gemm256_kernel(
    const unsigned short* __restrict__ A,
    const unsigned short* __restrict__ BT,
    const float* __restrict__ bias,
    unsigned short* __restrict__ Out0,
    unsigned short* __restrict__ Out1,
    int M, int N, int Kfull, int klen, int tilesPerSplit, int nwg)
{
  __shared__ __align__(16) unsigned short lds[81920]; // 160 KiB
  const int NT = N >> 8, MT = M >> 8;
  const int bid = blockIdx.x;
  const int wg = (bid & 7) * (nwg >> 3) + (bid >> 3);
  const int sp  = wg / tilesPerSplit;
  const int wgr = wg - sp * tilesPerSplit;
  const int e  = wgr / (MT*NT);
  const int r2 = wgr - e*(MT*NT);
  const int mt = r2 / NT, nt = r2 - mt*NT;
  const int k0 = sp * klen;
  const unsigned short* Ae = A + (size_t)e * M * Kfull;
  const unsigned short* Be = BT + (size_t)e * N * Kfull;
  const float* be = bias ? (bias + (size_t)e * N) : nullptr;
  unsigned short* Oe = (sp == 0 ? Out0 : Out1) + (size_t)e * M * N;
  const int m0 = mt*256, n0 = nt*256;

  const int tid = threadIdx.x, lane = tid & 63, w = tid >> 6;
  const int wr = w >> 2, wc = w & 3;   // 2 x 4 waves

  floatx4 acc[8][4];
  #pragma unroll
  for (int i = 0; i < 8; ++i)
    #pragma unroll
    for (int j = 0; j < 4; ++j) acc[i][j] = (floatx4){0.f, 0.f, 0.f, 0.f};

  const int r0s = tid >> 2;           // 0..127
  const int p0s = ((tid & 3) ^ ((r0s >> 1) & 3)) * 8;   // shorts
  const unsigned short* gA0 = Ae + (size_t)(m0 + r0s)*Kfull + k0 + p0s;
  const unsigned short* gA1 = gA0 + (size_t)128*Kfull;
  const unsigned short* gB0 = Be + (size_t)(n0 + r0s)*Kfull + k0 + p0s;
  const unsigned short* gB1 = gB0 + (size_t)128*Kfull;
  const int la0 = w*512, la1 = 4096 + w*512;   // wave-uniform LDS bases (shorts)

  const int fr = lane & 15, kq = lane >> 4;
  const int kqs = ((kq ^ ((fr >> 1) & 3)) * 8);
  const int aBase = (wr*128 + fr)*32 + kqs;            // + slot*8192 + mf*512
  const int bBase = 40960 + (wc*64 + fr)*32 + kqs;     // + slot*8192 + nf*512

  const int nk = klen >> 6;   // BK=64 tiles

#define STAGE_A(koff, s) do { \
    GLOAD16(gA0 + (size_t)(koff), lds + (s)*8192 + la0); \
    GLOAD16(gA1 + (size_t)(koff), lds + (s)*8192 + la1); } while(0)
#define STAGE_B(koff, s) do { \
    GLOAD16(gB0 + (size_t)(koff), lds + 40960 + (s)*8192 + la0); \
    GLOAD16(gB1 + (size_t)(koff), lds + 40960 + (s)*8192 + la1); } while(0)

  // prologue: halves 0,1 (tile 0) + half 2 (tile 1 kk0): 12 loads/thread
  STAGE_A(0, 0); STAGE_B(0, 0);
  STAGE_A(32, 1); STAGE_B(32, 1);
  STAGE_A(64, 2); STAGE_B(64, 2);
  asm volatile("s_waitcnt vmcnt(4)" ::: "memory");   // halves 0,1 landed
  BARRIER();

  int s0 = 0;  // slot of half 2t (advances +2 mod 5)
  for (int t = 0; t < nk; ++t) {
    const int s1  = (s0 + 1 >= 5) ? s0 - 4 : s0 + 1;   // half 2t+1
    const int sp3 = (s0 + 3 >= 5) ? s0 - 2 : s0 + 3;   // half 2t+3
    const int sp4 = (s0 + 4 >= 5) ? s0 - 1 : s0 + 4;   // half 2t+4
    const size_t kOdd = (size_t)(t + 1)*64 + 32;       // half 2t+3 k-offset
    const size_t kEv  = (size_t)(t + 2)*64;            // half 2t+4 k-offset
    const unsigned short* sA0 = lds + s0*8192;
    const unsigned short* sA1 = lds + s1*8192;
    short8 rB0[4], rA0lo[4], rA0hi[4], rB1[4], rA1lo[4], rA1hi[4];

    // ---- P1: issue rB0+rA0lo (8) | rA0hi (4); stage A(2t+3); MFMA Q1 ----
    #pragma unroll
    for (int nf = 0; nf < 4; ++nf) rB0[nf] = *(const short8*)(sA0 + bBase + nf*512);
    #pragma unroll
    for (int mf = 0; mf < 4; ++mf) rA0lo[mf] = *(const short8*)(sA0 + aBase + mf*512);
    SCHEDB();
    #pragma unroll
    for (int mf = 0; mf < 4; ++mf) rA0hi[mf] = *(const short8*)(sA0 + aBase + (mf+4)*512);
    if (t + 1 < nk) STAGE_A(kOdd, sp3);
    SCHEDB();
    asm volatile("s_waitcnt lgkmcnt(4)" ::: "memory");
    SCHEDB();
    __builtin_amdgcn_s_setprio(1);
    #pragma unroll
    for (int mf = 0; mf < 4; ++mf)
      #pragma unroll
      for (int nf = 0; nf < 4; ++nf)
        acc[mf][nf] = __builtin_amdgcn_mfma_f32_16x16x32_bf16(rA0lo[mf], rB0[nf], acc[mf][nf], 0, 0, 0);
    __builtin_amdgcn_s_setprio(0);
    SCHEDB();

    // ---- P2: issue rB1+rA1lo (8); stage B(2t+3); MFMA Q2 ----
    #pragma unroll
    for (int nf = 0; nf < 4; ++nf) rB1[nf] = *(const short8*)(sA1 + bBase + nf*512);
    #pragma unroll
    for (int mf = 0; mf < 4; ++mf) rA1lo[mf] = *(const short8*)(sA1 + aBase + mf*512);
    if (t + 1 < nk) STAGE_B(kOdd, sp3);
    SCHEDB();
    asm volatile("s_waitcnt lgkmcnt(8)" ::: "memory");
    SCHEDB();
    __builtin_amdgcn_s_setprio(1);
    #pragma unroll
    for (int mf = 0; mf < 4; ++mf)
      #pragma unroll
      for (int nf = 0; nf < 4; ++nf)
        acc[mf+4][nf] = __builtin_amdgcn_mfma_f32_16x16x32_bf16(rA0hi[mf], rB0[nf], acc[mf+4][nf], 0, 0, 0);
    __builtin_amdgcn_s_setprio(0);
    SCHEDB();

    // ---- P3: issue rA1hi (4); stage A(2t+4); MFMA Q3 ----
    #pragma unroll
    for (int mf = 0; mf < 4; ++mf) rA1hi[mf] = *(const short8*)(sA1 + aBase + (mf+4)*512);
    if (t + 2 < nk) STAGE_A(kEv, sp4);
    SCHEDB();
    asm volatile("s_waitcnt lgkmcnt(4)" ::: "memory");
    SCHEDB();
    __builtin_amdgcn_s_setprio(1);
    #pragma unroll
    for (int mf = 0; mf < 4; ++mf)
      #pragma unroll
      for (int nf = 0; nf < 4; ++nf)
        acc[mf][nf] = __builtin_amdgcn_mfma_f32_16x16x32_bf16(rA1lo[mf], rB1[nf], acc[mf][nf], 0, 0, 0);
    __builtin_amdgcn_s_setprio(0);
    SCHEDB();

    // ---- P4: stage B(2t+4); MFMA Q4; publish boundary ----
    if (t + 2 < nk) STAGE_B(kEv, sp4);
    SCHEDB();
    asm volatile("s_waitcnt lgkmcnt(0)" ::: "memory");
    SCHEDB();
    __builtin_amdgcn_s_setprio(1);
    #pragma unroll
    for (int mf = 0; mf < 4; ++mf)
      #pragma unroll
      for (int nf = 0; nf < 4; ++nf)
        acc[mf+4][nf] = __builtin_amdgcn_mfma_f32_16x16x32_bf16(rA1hi[mf], rB1[nf], acc[mf+4][nf], 0, 0, 0);
    __builtin_amdgcn_s_setprio(0);
    SCHEDB();

    if (t + 1 < nk) {
      if (t + 2 < nk) asm volatile("s_waitcnt vmcnt(4)" ::: "memory");
      else            asm volatile("s_waitcnt vmcnt(0)" ::: "memory");
      BARRIER();
    }
    s0 += 2; if (s0 >= 5) s0 -= 5;
  }
#undef STAGE_A
#undef STAGE_B

  // ---- epilogue: per-wave LDS scratch -> 128B-contiguous dwordx4 stores ----
  BARRIER();   // all ring ds_reads done; LDS reusable as scratch (DMA already drained)
  unsigned short* scr = lds + w*1152;          // 16 rows x 64 cols, row stride 72 shorts
  const int col = lane & 15, rbase = (lane >> 4) * 4;
  const int rrow = lane & 15, rchunk = lane >> 4;
  #pragma unroll
  for (int mf = 0; mf < 8; ++mf) {
    const int gr0 = m0 + wr*128 + mf*16;
    #pragma unroll
    for (int nf = 0; nf < 4; ++nf) {
      const float bv = be ? be[n0 + wc*64 + nf*16 + col] : 0.f;
      #pragma unroll
      for (int r = 0; r < 4; ++r) {
        float v = acc[mf][nf][r] + bv;
        if (RELU) v = fmaxf(v, 0.f);
        scr[(rbase + r)*72 + nf*16 + col] = f2bf(v);
      }
    }
    short8 o0 = *(const short8*)(scr + rrow*72 + rchunk*16);
    short8 o1 = *(const short8*)(scr + rrow*72 + rchunk*16 + 8);
    unsigned short* orow = Oe + (size_t)(gr0 + rrow)*N + n0 + wc*64 + rchunk*16;
    *(short8*)(orow) = o0;
    *(short8*)(orow + 8) = o1;
  }
}

// ---------------- Combine ----------------
__global__ void combine_kernel(const unsigned short* __restrict__ Y0,
                               const unsigned short* __restrict__ Y1,
                               const float* __restrict__ b2c,
                               const int* __restrict__ topk_e, const float* __restrict__ topk_p,
                               const int* __restrict__ pos_arr, float* __restrict__ out)
{
  int token = (int)((blockIdx.x * blockDim.x + threadIdx.x) >> 6);
  int lane = threadIdx.x & 63;
  if (token >= NTOK) return;
  int b = token / T_, t = token - b*T_;
  int s0 = b*S_ + t*2;
  float acc[16];
  #pragma unroll
  for (int i = 0; i < 16; ++i) acc[i] = 0.f;
  #pragma unroll
  for (int k = 0; k < 2; ++k) {
    int pos = pos_arr[s0 + k];
    if (pos < 0) continue;
    int e = topk_e[s0 + k];
    float p = topk_p[s0 + k];
    size_t rowoff = (((size_t)e*B_ + b)*CAP_ + pos) * C_;
    const unsigned short* yr0 = Y0 + rowoff;
    const unsigned short* yr1 = Y1 ? (Y1 + rowoff) : nullptr;
    const float* bb = b2c ? (b2c + (size_t)e * C_) : nullptr;
    #pragma unroll
    for (int i = 0; i < 4; ++i) {
      ushort4 v = ((const ushort4*)yr0)[i*64 + lane];
      float s0v = bf2f(v.x), s1v = bf2f(v.y), s2v = bf2f(v.z), s3v = bf2f(v.w);
      if (yr1) {
        ushort4 u = ((const ushort4*)yr1)[i*64 + lane];
        s0v += bf2f(u.x); s1v += bf2f(u.y); s2v += bf2f(u.z); s3v += bf2f(u.w);
      }
      if (bb) {
        float4 bv = ((const float4*)bb)[i*64 + lane];
        s0v += bv.x; s1v += bv.y; s2v += bv.z; s3v += bv.w;
      }
      acc[i*4+0] += p * s0v;
      acc[i*4+1] += p * s1v;
      acc[i*4+2] += p * s2v;
      acc[i*4+3] += p * s3v;
    }
  }
  float4* orow = (float4*)(out + (size_t)token * C_);
  #pragma unroll
  for (int i = 0; i < 4; ++i) {
    float4 o;
    o.x = acc[i*4+0]; o.y = acc[i*4+1]; o.z = acc[i*4+2]; o.w = acc[i*4+3];
    orow[i*64 + lane] = o;
  }
}

extern "C" void kernel_launch(void* const* d_in, const int* in_sizes, int n_in,
                              void* d_out, int out_size, void* d_ws, size_t ws_size,
                              hipStream_t stream)
{
  const float* x  = (const float*)d_in[0];
  const float* Wg = (const float*)d_in[1];
  const float* bg = (const float*)d_in[2];
  const float* W1 = (const float*)d_in[3];
  const float* b1 = (const float*)d_in[4];
  const float* W2 = (const float*)d_in[5];
  const float* b2 = (const float*)d_in[6];
  float* out = (float*)d_out;

  char* ws = (char*)d_ws;
  size_t off = 0;
  auto alloc = [&](size_t bytes) -> char* {
    char* p = ws + off;
    off = (off + bytes + 255) & ~(size_t)255;
    return p;
  };
  int*   topk_e  = (int*)  alloc((size_t)NTOK * K_ * 4);
  float* topk_p  = (float*)alloc((size_t)NTOK * K_ * 4);
  int*   pos_arr = (int*)  alloc((size_t)B_ * S_ * 4);
  int*   slot_src= (int*)  alloc((size_t)E_ * B_ * CAP_ * 4);
  int*   counts  = (int*)  alloc((size_t)E_ * B_ * 4);
  unsigned short* Ybuf = (unsigned short*)alloc((size_t)E_ * ROWS_PER_E * C_ * 2);
  size_t fixed = off;
  const size_t perE = (size_t)C_ * DFF_ * 2
                    + (size_t)ROWS_PER_E * C_ * 2
                    + (size_t)ROWS_PER_E * DFF_ * 2
                    + 3 * 256;
  int k = 8;
  while (k > 1 && fixed + (size_t)k * perE > ws_size) k >>= 1;
  unsigned short* Wt = (unsigned short*)alloc((size_t)k * C_ * DFF_ * 2);
  unsigned short* Xd = (unsigned short*)alloc((size_t)k * ROWS_PER_E * C_ * 2);
  unsigned short* Hb = (unsigned short*)alloc((size_t)k * ROWS_PER_E * DFF_ * 2);

  router_kernel<<<NTOK/4, 256, 0, stream>>>(x, Wg, bg, topk_e, topk_p);
  scan_kernel<<<B_, 256, 0, stream>>>(topk_e, pos_arr, slot_src, counts);

  const bool splitK2 = (k == 8);

  for (int eb = 0; eb < E_; eb += k) {
    transpose_conv_kernel<<<dim3(DFF_/32, C_/64, k), 256, 0, stream>>>(
        W1 + (size_t)eb * C_ * DFF_, Wt, C_, DFF_);
    dispatch_kernel<<<(k * ROWS_PER_E) / 4, 256, 0, stream>>>(x, slot_src, counts, Xd, eb, k);
    // H = relu(Xd @ W1 + b1)
    {
      int tiles = k * (ROWS_PER_E/256) * (DFF_/256);
      gemm256_kernel<1><<<tiles, 512, 0, stream>>>(
          Xd, Wt, b1 + (size_t)eb * DFF_, Hb, Hb, ROWS_PER_E, DFF_, C_, C_, tiles, tiles);
    }
    transpose_conv_kernel<<<dim3(C_/32, DFF_/64, k), 256, 0, stream>>>(
        W2 + (size_t)eb * DFF_ * C_, Wt, DFF_, C_);
    // Y = H @ W2
    {
      int tiles = k * (ROWS_PER_E/256) * (C_/256);
      if (splitK2) {
        gemm256_kernel<0><<<2*tiles, 512, 0, stream>>>(
            Hb, Wt, nullptr, Ybuf, Xd, ROWS_PER_E, C_, DFF_, DFF_/2, tiles, 2*tiles);
      } else {
        gemm256_kernel<0><<<tiles, 512, 0, stream>>>(
            Hb, Wt, b2 + (size_t)eb * C_, Ybuf + (size_t)eb * ROWS_PER_E * C_,
            Ybuf + (size_t)eb * ROWS_PER_E * C_, ROWS_PER_E, C_, DFF_, DFF_, tiles, tiles);
      }
    }
  }

  combine_kernel<<<NTOK/4, 256, 0, stream>>>(
      Ybuf, splitK2 ? Xd : nullptr, splitK2 ? b2 : nullptr,
      topk_e, topk_p, pos_arr, out);
}

// Round 14
// 565.332 us; speedup vs baseline: 1.0458x; 1.0458x over previous
//
#include <hip/hip_runtime.h>
#include <stdint.h>

#define B_ 8
#define T_ 2048
#define C_ 1024
#define E_ 8
#define K_ 2
#define CAP_ 320
#define DFF_ 4096
#define S_ (T_*K_)
#define NTOK (B_*T_)
#define ROWS_PER_E (B_*CAP_) // 2560

typedef __attribute__((ext_vector_type(8))) short short8;
typedef __attribute__((ext_vector_type(4))) float floatx4;

__device__ __forceinline__ unsigned short f2bf(float f) {
  union { float f; unsigned u; } v; v.f = f;
  unsigned r = v.u + 0x7fffu + ((v.u >> 16) & 1u);
  return (unsigned short)(r >> 16);
}
__device__ __forceinline__ float bf2f(unsigned short h) {
  union { unsigned u; float f; } v; v.u = ((unsigned)h) << 16;
  return v.f;
}

#define GLOAD16(g, l) __builtin_amdgcn_global_load_lds( \
    (const __attribute__((address_space(1))) void*)(g), \
    (__attribute__((address_space(3))) void*)(l), 16, 0, 0)

#define BARRIER() asm volatile("s_barrier" ::: "memory")
#define SCHEDB() __builtin_amdgcn_sched_barrier(0)

// ---------------- Router: fp64 logits, softmax, top-2 ----------------
__global__ void router_kernel(const float* __restrict__ x, const float* __restrict__ Wg,
                              const float* __restrict__ bg,
                              int* __restrict__ topk_e, float* __restrict__ topk_p)
{
  int token = (int)((blockIdx.x * blockDim.x + threadIdx.x) >> 6);
  int lane = threadIdx.x & 63;
  if (token >= NTOK) return;
  const float* xr = x + (size_t)token * C_;
  double acc[E_];
  #pragma unroll
  for (int e = 0; e < E_; ++e) acc[e] = 0.0;
  for (int c = lane; c < C_; c += 64) {
    double xv = (double)xr[c];
    const float4* w4 = (const float4*)(Wg + (size_t)c * E_);
    float4 wa = w4[0], wb = w4[1];
    acc[0] += xv * (double)wa.x; acc[1] += xv * (double)wa.y;
    acc[2] += xv * (double)wa.z; acc[3] += xv * (double)wa.w;
    acc[4] += xv * (double)wb.x; acc[5] += xv * (double)wb.y;
    acc[6] += xv * (double)wb.z; acc[7] += xv * (double)wb.w;
  }
  #pragma unroll
  for (int off = 32; off; off >>= 1) {
    #pragma unroll
    for (int e = 0; e < E_; ++e) acc[e] += __shfl_down(acc[e], off, 64);
  }
  if (lane == 0) {
    double lg[E_];
    double mx = -1e300;
    #pragma unroll
    for (int e = 0; e < E_; ++e) { lg[e] = acc[e] + (double)bg[e]; mx = fmax(mx, lg[e]); }
    double se = 0.0, pr[E_];
    #pragma unroll
    for (int e = 0; e < E_; ++e) { pr[e] = exp(lg[e] - mx); se += pr[e]; }
    #pragma unroll
    for (int e = 0; e < E_; ++e) pr[e] /= se;
    int e0 = 0;
    #pragma unroll
    for (int e = 1; e < E_; ++e) if (pr[e] > pr[e0]) e0 = e;
    int e1 = -1;
    #pragma unroll
    for (int e = 0; e < E_; ++e) {
      if (e == e0) continue;
      if (e1 < 0 || pr[e] > pr[e1]) e1 = e;
    }
    topk_e[token*2+0] = e0; topk_p[token*2+0] = (float)pr[e0];
    topk_e[token*2+1] = e1; topk_p[token*2+1] = (float)pr[e1];
  }
}

// ---------------- Scan ----------------
__global__ void scan_kernel(const int* __restrict__ topk_e,
                            int* __restrict__ pos_arr, int* __restrict__ slot_src,
                            int* __restrict__ counts)
{
  const int b = blockIdx.x;
  const int tid = threadIdx.x;
  const int PT = S_ / 256; // 16
  __shared__ int cnt[256][E_];
  int e_loc[16];
  int local[E_];
  #pragma unroll
  for (int e = 0; e < E_; ++e) local[e] = 0;
  const int* te = topk_e + (size_t)b * S_;
  for (int j = 0; j < PT; ++j) {
    int e = te[tid*PT + j];
    e_loc[j] = e;
    local[e]++;
  }
  #pragma unroll
  for (int e = 0; e < E_; ++e) cnt[tid][e] = local[e];
  __syncthreads();
  if (tid < E_) {
    int run = 0;
    for (int i = 0; i < 256; ++i) { int v = cnt[i][tid]; cnt[i][tid] = run; run += v; }
    counts[tid*B_ + b] = run;
  }
  __syncthreads();
  int base[E_];
  #pragma unroll
  for (int e = 0; e < E_; ++e) base[e] = cnt[tid][e];
  for (int j = 0; j < PT; ++j) {
    int e = e_loc[j];
    int p = base[e]++;
    int s = tid*PT + j;
    if (p < CAP_) {
      pos_arr[(size_t)b*S_ + s] = p;
      slot_src[((size_t)e*B_ + b)*CAP_ + p] = s >> 1;
    } else {
      pos_arr[(size_t)b*S_ + s] = -1;
    }
  }
}

// ---------------- Transpose + fp32->bf16 ----------------
__global__ void transpose_conv_kernel(const float* __restrict__ in, unsigned short* __restrict__ out,
                                      int R, int Cc)
{
  __shared__ float tile[64][33];
  const int e = blockIdx.z;
  const float* ine = in + (size_t)e * R * Cc;
  unsigned short* oute = out + (size_t)e * R * Cc;
  const int c0 = blockIdx.x * 32, r0 = blockIdx.y * 64;
  const int tx = threadIdx.x & 7, ty = threadIdx.x >> 3;
  #pragma unroll
  for (int p = 0; p < 2; ++p) {
    const int rr = p*32 + ty;
    float4 v = *(const float4*)(ine + (size_t)(r0 + rr) * Cc + c0 + tx*4);
    tile[rr][tx*4+0] = v.x; tile[rr][tx*4+1] = v.y;
    tile[rr][tx*4+2] = v.z; tile[rr][tx*4+3] = v.w;
  }
  __syncthreads();
  short8 s;
  #pragma unroll
  for (int j = 0; j < 8; ++j) s[j] = (short)f2bf(tile[tx*8+j][ty]);
  *(short8*)(oute + (size_t)(c0 + ty) * R + r0 + tx*8) = s;
}

// ---------------- Dispatch ----------------
__global__ void dispatch_kernel(const float* __restrict__ x, const int* __restrict__ slot_src,
                                const int* __restrict__ counts, unsigned short* __restrict__ Xd,
                                int e_base, int nexp)
{
  int row = (int)((blockIdx.x * blockDim.x + threadIdx.x) >> 6);
  int lane = threadIdx.x & 63;
  int total = nexp * B_ * CAP_;
  if (row >= total) return;
  int el = row / (B_*CAP_);
  int rem = row - el*(B_*CAP_);
  int b = rem / CAP_, slot = rem - b*CAP_;
  int eg = e_base + el;
  int cnt = counts[eg*B_ + b]; if (cnt > CAP_) cnt = CAP_;
  unsigned short* orow = Xd + (size_t)row * C_;
  if (slot < cnt) {
    int t = slot_src[((size_t)eg*B_ + b)*CAP_ + slot];
    const float4* xr = (const float4*)(x + ((size_t)b*T_ + t)*C_);
    #pragma unroll
    for (int i = 0; i < C_/256; ++i) {
      float4 v = xr[i*64 + lane];
      ushort4 o;
      o.x = f2bf(v.x); o.y = f2bf(v.y); o.z = f2bf(v.z); o.w = f2bf(v.w);
      ((ushort4*)orow)[i*64 + lane] = o;
    }
  } else {
    ushort4 z; z.x = z.y = z.z = z.w = 0;
    #pragma unroll
    for (int i = 0; i < C_/256; ++i) ((ushort4*)orow)[i*64 + lane] = z;
  }
}

// ---------------- GEMM 256x256, BK=64, mod-5 half-ring, ONE barrier/tile ----------------
// A [e][M][Kfull] bf16 x BT [e][N][Kfull] bf16 (+bias if non-null, opt relu) -> Out bf16.
// 512 threads = 8 waves (2M x 4N), per-wave 128x64 (8x4 16x16 frags, kk=2 K-halves).
// LDS 160KB: per operand a 5-SLOT ring of K-HALF tiles (256 rows x 32 shorts = 16KB);
// half h lives in slot h%5. mod-5 makes every stage target a slot whose half was
// fully read in tile t-1 (all reads retire before the t-1 boundary barrier via
// each wave's P4 lgkmcnt(0)) -> NO mid-tile WAR barrier needed. One barrier/tile.
// Register pipeline: fragment ds_reads issued one quadrant ahead with counted
// lgkmcnt(4/8/4/0) so MFMA clusters run while next reads are in flight.
// Stages: P1 A(2t+3), P2 B(2t+3), P3 A(2t+4), P4 B(2t+4); boundary vmcnt(4)
// drains exactly halves 2t+2,2t+3 (= tile t+1); never 0 until t+2==nk.
// T2 swizzle (0-conflict, verified r10/r11): 16B-chunk ^= ((row>>1)&3) on BOTH
// staging source and ds_read offsets; LDS dest linear (rule #21).
template<int RELU>
__global__ __launch_bounds__(512) void gemm256_kernel(
    const unsigned short* __restrict__ A,
    const unsigned short* __restrict__ BT,
    const float* __restrict__ bias,
    unsigned short* __restrict__ Out0,
    unsigned short* __restrict__ Out1,
    int M, int N, int Kfull, int klen, int tilesPerSplit, int nwg)
{
  __shared__ __align__(16) unsigned short lds[81920]; // 160 KiB: A 5x8192, B 5x8192 shorts
  const int NT = N >> 8, MT = M >> 8;
  const int bid = blockIdx.x;
  const int wg = (bid & 7) * (nwg >> 3) + (bid >> 3);
  const int sp  = wg / tilesPerSplit;
  const int wgr = wg - sp * tilesPerSplit;
  const int e  = wgr / (MT*NT);
  const int r2 = wgr - e*(MT*NT);
  const int mt = r2 / NT, nt = r2 - mt*NT;
  const int k0 = sp * klen;
  const unsigned short* Ae = A + (size_t)e * M * Kfull;
  const unsigned short* Be = BT + (size_t)e * N * Kfull;
  const float* be = bias ? (bias + (size_t)e * N) : nullptr;
  unsigned short* Oe = (sp == 0 ? Out0 : Out1) + (size_t)e * M * N;
  const int m0 = mt*256, n0 = nt*256;

  const int tid = threadIdx.x, lane = tid & 63, w = tid >> 6;
  const int wr = w >> 2, wc = w & 3;   // 2 x 4 waves

  floatx4 acc[8][4];
  #pragma unroll
  for (int i = 0; i < 8; ++i)
    #pragma unroll
    for (int j = 0; j < 4; ++j) acc[i][j] = (floatx4){0.f, 0.f, 0.f, 0.f};

  // Staging: one K-half = 256 rows x 32 shorts = 1024 chunks of 16B; thread covers
  // chunks tid (rows 0-127) and 512+tid (rows 128-255; +128 = row bit 7, XOR same).
  const int r0s = tid >> 2;           // 0..127
  const int p0s = ((tid & 3) ^ ((r0s >> 1) & 3)) * 8;   // shorts
  const unsigned short* gA0 = Ae + (size_t)(m0 + r0s)*Kfull + k0 + p0s;
  const unsigned short* gA1 = gA0 + (size_t)128*Kfull;
  const unsigned short* gB0 = Be + (size_t)(n0 + r0s)*Kfull + k0 + p0s;
  const unsigned short* gB1 = gB0 + (size_t)128*Kfull;
  const int la0 = w*512, la1 = 4096 + w*512;   // wave-uniform LDS bases (shorts)

  // Fragment reads: fr = lane&15, kq = lane>>4; (row>>1)&3 == (fr>>1)&3.
  const int fr = lane & 15, kq = lane >> 4;
  const int kqs = ((kq ^ ((fr >> 1) & 3)) * 8);
  const int aBase = (wr*128 + fr)*32 + kqs;            // + slot*8192 + mf*512
  const int bBase = 40960 + (wc*64 + fr)*32 + kqs;     // + slot*8192 + nf*512

  const int nk = klen >> 6;   // BK=64 tiles

#define STAGE_A(koff, s) do { \
    GLOAD16(gA0 + (size_t)(koff), lds + (s)*8192 + la0); \
    GLOAD16(gA1 + (size_t)(koff), lds + (s)*8192 + la1); } while(0)
#define STAGE_B(koff, s) do { \
    GLOAD16(gB0 + (size_t)(koff), lds + 40960 + (s)*8192 + la0); \
    GLOAD16(gB1 + (size_t)(koff), lds + 40960 + (s)*8192 + la1); } while(0)

  // prologue: halves 0,1 (tile 0) + half 2 (tile 1 kk0): 12 loads/thread
  STAGE_A(0, 0); STAGE_B(0, 0);
  STAGE_A(32, 1); STAGE_B(32, 1);
  STAGE_A(64, 2); STAGE_B(64, 2);
  asm volatile("s_waitcnt vmcnt(4)" ::: "memory");   // halves 0,1 landed
  BARRIER();

  int s0 = 0;  // slot of half 2t (advances +2 mod 5)
  for (int t = 0; t < nk; ++t) {
    const int s1  = (s0 + 1 >= 5) ? s0 - 4 : s0 + 1;   // half 2t+1
    const int sp3 = (s0 + 3 >= 5) ? s0 - 2 : s0 + 3;   // half 2t+3
    const int sp4 = (s0 + 4 >= 5) ? s0 - 1 : s0 + 4;   // half 2t+4
    const size_t kOdd = (size_t)(t + 1)*64 + 32;       // half 2t+3 k-offset
    const size_t kEv  = (size_t)(t + 2)*64;            // half 2t+4 k-offset
    const unsigned short* sA0 = lds + s0*8192;
    const unsigned short* sA1 = lds + s1*8192;
    short8 rB0[4], rA0lo[4], rA0hi[4], rB1[4], rA1lo[4], rA1hi[4];

    // ---- P1: issue rB0+rA0lo (8) | rA0hi (4); stage A(2t+3); MFMA Q1 ----
    #pragma unroll
    for (int nf = 0; nf < 4; ++nf) rB0[nf] = *(const short8*)(sA0 + bBase + nf*512);
    #pragma unroll
    for (int mf = 0; mf < 4; ++mf) rA0lo[mf] = *(const short8*)(sA0 + aBase + mf*512);
    SCHEDB();
    #pragma unroll
    for (int mf = 0; mf < 4; ++mf) rA0hi[mf] = *(const short8*)(sA0 + aBase + (mf+4)*512);
    if (t + 1 < nk) STAGE_A(kOdd, sp3);
    SCHEDB();
    asm volatile("s_waitcnt lgkmcnt(4)" ::: "memory");  // rB0,rA0lo ready; rA0hi flying
    SCHEDB();
    __builtin_amdgcn_s_setprio(1);
    #pragma unroll
    for (int mf = 0; mf < 4; ++mf)
      #pragma unroll
      for (int nf = 0; nf < 4; ++nf)
        acc[mf][nf] = __builtin_amdgcn_mfma_f32_16x16x32_bf16(rA0lo[mf], rB0[nf], acc[mf][nf], 0, 0, 0);
    __builtin_amdgcn_s_setprio(0);
    SCHEDB();

    // ---- P2: issue rB1+rA1lo (8); stage B(2t+3); MFMA Q2 (no barrier: mod-5 WAR-safe) ----
    #pragma unroll
    for (int nf = 0; nf < 4; ++nf) rB1[nf] = *(const short8*)(sA1 + bBase + nf*512);
    #pragma unroll
    for (int mf = 0; mf < 4; ++mf) rA1lo[mf] = *(const short8*)(sA1 + aBase + mf*512);
    if (t + 1 < nk) STAGE_B(kOdd, sp3);
    SCHEDB();
    asm volatile("s_waitcnt lgkmcnt(8)" ::: "memory");  // rA0hi ready
    SCHEDB();
    __builtin_amdgcn_s_setprio(1);
    #pragma unroll
    for (int mf = 0; mf < 4; ++mf)
      #pragma unroll
      for (int nf = 0; nf < 4; ++nf)
        acc[mf+4][nf] = __builtin_amdgcn_mfma_f32_16x16x32_bf16(rA0hi[mf], rB0[nf], acc[mf+4][nf], 0, 0, 0);
    __builtin_amdgcn_s_setprio(0);
    SCHEDB();

    // ---- P3: issue rA1hi (4); stage A(2t+4); MFMA Q3 ----
    #pragma unroll
    for (int mf = 0; mf < 4; ++mf) rA1hi[mf] = *(const short8*)(sA1 + aBase + (mf+4)*512);
    if (t + 2 < nk) STAGE_A(kEv, sp4);
    SCHEDB();
    asm volatile("s_waitcnt lgkmcnt(4)" ::: "memory");  // rB1,rA1lo ready; rA1hi flying
    SCHEDB();
    __builtin_amdgcn_s_setprio(1);
    #pragma unroll
    for (int mf = 0; mf < 4; ++mf)
      #pragma unroll
      for (int nf = 0; nf < 4; ++nf)
        acc[mf][nf] = __builtin_amdgcn_mfma_f32_16x16x32_bf16(rA1lo[mf], rB1[nf], acc[mf][nf], 0, 0, 0);
    __builtin_amdgcn_s_setprio(0);
    SCHEDB();

    // ---- P4: stage B(2t+4); MFMA Q4; publish boundary ----
    if (t + 2 < nk) STAGE_B(kEv, sp4);
    SCHEDB();
    asm volatile("s_waitcnt lgkmcnt(0)" ::: "memory");  // rA1hi ready
    SCHEDB();
    __builtin_amdgcn_s_setprio(1);
    #pragma unroll
    for (int mf = 0; mf < 4; ++mf)
      #pragma unroll
      for (int nf = 0; nf < 4; ++nf)
        acc[mf+4][nf] = __builtin_amdgcn_mfma_f32_16x16x32_bf16(rA1hi[mf], rB1[nf], acc[mf+4][nf], 0, 0, 0);
    __builtin_amdgcn_s_setprio(0);
    SCHEDB();

    if (t + 1 < nk) {
      if (t + 2 < nk) asm volatile("s_waitcnt vmcnt(4)" ::: "memory");
      else            asm volatile("s_waitcnt vmcnt(0)" ::: "memory");
      BARRIER();   // tile t+1 (halves 2t+2, 2t+3) published
    }
    s0 += 2; if (s0 >= 5) s0 -= 5;
  }
#undef STAGE_A
#undef STAGE_B

  // epilogue: C/D layout col = lane&15, row = (lane>>4)*4 + reg
  const int col = lane & 15, rbase = (lane >> 4) * 4;
  #pragma unroll
  for (int mf = 0; mf < 8; ++mf) {
    const int gr0 = m0 + wr*128 + mf*16 + rbase;
    #pragma unroll
    for (int nf = 0; nf < 4; ++nf) {
      const int gc = n0 + wc*64 + nf*16 + col;
      const float bv = be ? be[gc] : 0.f;
      #pragma unroll
      for (int r = 0; r < 4; ++r) {
        float v = acc[mf][nf][r] + bv;
        if (RELU) v = fmaxf(v, 0.f);
        Oe[(size_t)(gr0 + r)*N + gc] = f2bf(v);
      }
    }
  }
}

// ---------------- Combine ----------------
__global__ void combine_kernel(const unsigned short* __restrict__ Y0,
                               const unsigned short* __restrict__ Y1,
                               const float* __restrict__ b2c,
                               const int* __restrict__ topk_e, const float* __restrict__ topk_p,
                               const int* __restrict__ pos_arr, float* __restrict__ out)
{
  int token = (int)((blockIdx.x * blockDim.x + threadIdx.x) >> 6);
  int lane = threadIdx.x & 63;
  if (token >= NTOK) return;
  int b = token / T_, t = token - b*T_;
  int s0 = b*S_ + t*2;
  float acc[16];
  #pragma unroll
  for (int i = 0; i < 16; ++i) acc[i] = 0.f;
  #pragma unroll
  for (int k = 0; k < 2; ++k) {
    int pos = pos_arr[s0 + k];
    if (pos < 0) continue;
    int e = topk_e[s0 + k];
    float p = topk_p[s0 + k];
    size_t rowoff = (((size_t)e*B_ + b)*CAP_ + pos) * C_;
    const unsigned short* yr0 = Y0 + rowoff;
    const unsigned short* yr1 = Y1 ? (Y1 + rowoff) : nullptr;
    const float* bb = b2c ? (b2c + (size_t)e * C_) : nullptr;
    #pragma unroll
    for (int i = 0; i < 4; ++i) {
      ushort4 v = ((const ushort4*)yr0)[i*64 + lane];
      float s0v = bf2f(v.x), s1v = bf2f(v.y), s2v = bf2f(v.z), s3v = bf2f(v.w);
      if (yr1) {
        ushort4 u = ((const ushort4*)yr1)[i*64 + lane];
        s0v += bf2f(u.x); s1v += bf2f(u.y); s2v += bf2f(u.z); s3v += bf2f(u.w);
      }
      if (bb) {
        float4 bv = ((const float4*)bb)[i*64 + lane];
        s0v += bv.x; s1v += bv.y; s2v += bv.z; s3v += bv.w;
      }
      acc[i*4+0] += p * s0v;
      acc[i*4+1] += p * s1v;
      acc[i*4+2] += p * s2v;
      acc[i*4+3] += p * s3v;
    }
  }
  float4* orow = (float4*)(out + (size_t)token * C_);
  #pragma unroll
  for (int i = 0; i < 4; ++i) {
    float4 o;
    o.x = acc[i*4+0]; o.y = acc[i*4+1]; o.z = acc[i*4+2]; o.w = acc[i*4+3];
    orow[i*64 + lane] = o;
  }
}

extern "C" void kernel_launch(void* const* d_in, const int* in_sizes, int n_in,
                              void* d_out, int out_size, void* d_ws, size_t ws_size,
                              hipStream_t stream)
{
  const float* x  = (const float*)d_in[0];
  const float* Wg = (const float*)d_in[1];
  const float* bg = (const float*)d_in[2];
  const float* W1 = (const float*)d_in[3];
  const float* b1 = (const float*)d_in[4];
  const float* W2 = (const float*)d_in[5];
  const float* b2 = (const float*)d_in[6];
  float* out = (float*)d_out;

  char* ws = (char*)d_ws;
  size_t off = 0;
  auto alloc = [&](size_t bytes) -> char* {
    char* p = ws + off;
    off = (off + bytes + 255) & ~(size_t)255;
    return p;
  };
  int*   topk_e  = (int*)  alloc((size_t)NTOK * K_ * 4);
  float* topk_p  = (float*)alloc((size_t)NTOK * K_ * 4);
  int*   pos_arr = (int*)  alloc((size_t)B_ * S_ * 4);
  int*   slot_src= (int*)  alloc((size_t)E_ * B_ * CAP_ * 4);
  int*   counts  = (int*)  alloc((size_t)E_ * B_ * 4);
  unsigned short* Ybuf = (unsigned short*)alloc((size_t)E_ * ROWS_PER_E * C_ * 2);
  size_t fixed = off;
  const size_t perE = (size_t)C_ * DFF_ * 2
                    + (size_t)ROWS_PER_E * C_ * 2
                    + (size_t)ROWS_PER_E * DFF_ * 2
                    + 3 * 256;
  int k = 8;
  while (k > 1 && fixed + (size_t)k * perE > ws_size) k >>= 1;
  unsigned short* Wt = (unsigned short*)alloc((size_t)k * C_ * DFF_ * 2);
  unsigned short* Xd = (unsigned short*)alloc((size_t)k * ROWS_PER_E * C_ * 2);
  unsigned short* Hb = (unsigned short*)alloc((size_t)k * ROWS_PER_E * DFF_ * 2);

  router_kernel<<<NTOK/4, 256, 0, stream>>>(x, Wg, bg, topk_e, topk_p);
  scan_kernel<<<B_, 256, 0, stream>>>(topk_e, pos_arr, slot_src, counts);

  const bool splitK2 = (k == 8);

  for (int eb = 0; eb < E_; eb += k) {
    transpose_conv_kernel<<<dim3(DFF_/32, C_/64, k), 256, 0, stream>>>(
        W1 + (size_t)eb * C_ * DFF_, Wt, C_, DFF_);
    dispatch_kernel<<<(k * ROWS_PER_E) / 4, 256, 0, stream>>>(x, slot_src, counts, Xd, eb, k);
    // H = relu(Xd @ W1 + b1)
    {
      int tiles = k * (ROWS_PER_E/256) * (DFF_/256);
      gemm256_kernel<1><<<tiles, 512, 0, stream>>>(
          Xd, Wt, b1 + (size_t)eb * DFF_, Hb, Hb, ROWS_PER_E, DFF_, C_, C_, tiles, tiles);
    }
    transpose_conv_kernel<<<dim3(C_/32, DFF_/64, k), 256, 0, stream>>>(
        W2 + (size_t)eb * DFF_ * C_, Wt, DFF_, C_);
    // Y = H @ W2
    {
      int tiles = k * (ROWS_PER_E/256) * (C_/256);
      if (splitK2) {
        gemm256_kernel<0><<<2*tiles, 512, 0, stream>>>(
            Hb, Wt, nullptr, Ybuf, Xd, ROWS_PER_E, C_, DFF_, DFF_/2, tiles, 2*tiles);
      } else {
        gemm256_kernel<0><<<tiles, 512, 0, stream>>>(
            Hb, Wt, b2 + (size_t)eb * C_, Ybuf + (size_t)eb * ROWS_PER_E * C_,
            Ybuf + (size_t)eb * ROWS_PER_E * C_, ROWS_PER_E, C_, DFF_, DFF_, tiles, tiles);
      }
    }
  }

  combine_kernel<<<NTOK/4, 256, 0, stream>>>(
      Ybuf, splitK2 ? Xd : nullptr, splitK2 ? b2 : nullptr,
      topk_e, topk_p, pos_arr, out);
}

// Round 15
// 561.009 us; speedup vs baseline: 1.0538x; 1.0077x over previous
//
#include <hip/hip_runtime.h>
#include <stdint.h>

#define B_ 8
#define T_ 2048
#define C_ 1024
#define E_ 8
#define K_ 2
#define CAP_ 320
#define DFF_ 4096
#define S_ (T_*K_)
#define NTOK (B_*T_)
#define ROWS_PER_E (B_*CAP_) // 2560

typedef __attribute__((ext_vector_type(8))) short short8;
typedef __attribute__((ext_vector_type(4))) float floatx4;

__device__ __forceinline__ unsigned short f2bf(float f) {
  union { float f; unsigned u; } v; v.f = f;
  unsigned r = v.u + 0x7fffu + ((v.u >> 16) & 1u);
  return (unsigned short)(r >> 16);
}
__device__ __forceinline__ float bf2f(unsigned short h) {
  union { unsigned u; float f; } v; v.u = ((unsigned)h) << 16;
  return v.f;
}

#define GLOAD16(g, l) __builtin_amdgcn_global_load_lds( \
    (const __attribute__((address_space(1))) void*)(g), \
    (__attribute__((address_space(3))) void*)(l), 16, 0, 0)

#define BARRIER() asm volatile("s_barrier" ::: "memory")
#define SCHEDB() __builtin_amdgcn_sched_barrier(0)

// ---------------- Router: fp64 logits, softmax, top-2 ----------------
__global__ void router_kernel(const float* __restrict__ x, const float* __restrict__ Wg,
                              const float* __restrict__ bg,
                              int* __restrict__ topk_e, float* __restrict__ topk_p)
{
  int token = (int)((blockIdx.x * blockDim.x + threadIdx.x) >> 6);
  int lane = threadIdx.x & 63;
  if (token >= NTOK) return;
  const float* xr = x + (size_t)token * C_;
  double acc[E_];
  #pragma unroll
  for (int e = 0; e < E_; ++e) acc[e] = 0.0;
  for (int c = lane; c < C_; c += 64) {
    double xv = (double)xr[c];
    const float4* w4 = (const float4*)(Wg + (size_t)c * E_);
    float4 wa = w4[0], wb = w4[1];
    acc[0] += xv * (double)wa.x; acc[1] += xv * (double)wa.y;
    acc[2] += xv * (double)wa.z; acc[3] += xv * (double)wa.w;
    acc[4] += xv * (double)wb.x; acc[5] += xv * (double)wb.y;
    acc[6] += xv * (double)wb.z; acc[7] += xv * (double)wb.w;
  }
  #pragma unroll
  for (int off = 32; off; off >>= 1) {
    #pragma unroll
    for (int e = 0; e < E_; ++e) acc[e] += __shfl_down(acc[e], off, 64);
  }
  if (lane == 0) {
    double lg[E_];
    double mx = -1e300;
    #pragma unroll
    for (int e = 0; e < E_; ++e) { lg[e] = acc[e] + (double)bg[e]; mx = fmax(mx, lg[e]); }
    double se = 0.0, pr[E_];
    #pragma unroll
    for (int e = 0; e < E_; ++e) { pr[e] = exp(lg[e] - mx); se += pr[e]; }
    #pragma unroll
    for (int e = 0; e < E_; ++e) pr[e] /= se;
    int e0 = 0;
    #pragma unroll
    for (int e = 1; e < E_; ++e) if (pr[e] > pr[e0]) e0 = e;
    int e1 = -1;
    #pragma unroll
    for (int e = 0; e < E_; ++e) {
      if (e == e0) continue;
      if (e1 < 0 || pr[e] > pr[e1]) e1 = e;
    }
    topk_e[token*2+0] = e0; topk_p[token*2+0] = (float)pr[e0];
    topk_e[token*2+1] = e1; topk_p[token*2+1] = (float)pr[e1];
  }
}

// ---------------- Scan ----------------
__global__ void scan_kernel(const int* __restrict__ topk_e,
                            int* __restrict__ pos_arr, int* __restrict__ slot_src,
                            int* __restrict__ counts)
{
  const int b = blockIdx.x;
  const int tid = threadIdx.x;
  const int PT = S_ / 256; // 16
  __shared__ int cnt[256][E_];
  int e_loc[16];
  int local[E_];
  #pragma unroll
  for (int e = 0; e < E_; ++e) local[e] = 0;
  const int* te = topk_e + (size_t)b * S_;
  for (int j = 0; j < PT; ++j) {
    int e = te[tid*PT + j];
    e_loc[j] = e;
    local[e]++;
  }
  #pragma unroll
  for (int e = 0; e < E_; ++e) cnt[tid][e] = local[e];
  __syncthreads();
  if (tid < E_) {
    int run = 0;
    for (int i = 0; i < 256; ++i) { int v = cnt[i][tid]; cnt[i][tid] = run; run += v; }
    counts[tid*B_ + b] = run;
  }
  __syncthreads();
  int base[E_];
  #pragma unroll
  for (int e = 0; e < E_; ++e) base[e] = cnt[tid][e];
  for (int j = 0; j < PT; ++j) {
    int e = e_loc[j];
    int p = base[e]++;
    int s = tid*PT + j;
    if (p < CAP_) {
      pos_arr[(size_t)b*S_ + s] = p;
      slot_src[((size_t)e*B_ + b)*CAP_ + p] = s >> 1;
    } else {
      pos_arr[(size_t)b*S_ + s] = -1;
    }
  }
}

// ---------------- Transpose + fp32->bf16 (standalone, used for W2) ----------------
__global__ void transpose_conv_kernel(const float* __restrict__ in, unsigned short* __restrict__ out,
                                      int R, int Cc)
{
  __shared__ float tile[64][33];
  const int e = blockIdx.z;
  const float* ine = in + (size_t)e * R * Cc;
  unsigned short* oute = out + (size_t)e * R * Cc;
  const int c0 = blockIdx.x * 32, r0 = blockIdx.y * 64;
  const int tx = threadIdx.x & 7, ty = threadIdx.x >> 3;
  #pragma unroll
  for (int p = 0; p < 2; ++p) {
    const int rr = p*32 + ty;
    float4 v = *(const float4*)(ine + (size_t)(r0 + rr) * Cc + c0 + tx*4);
    tile[rr][tx*4+0] = v.x; tile[rr][tx*4+1] = v.y;
    tile[rr][tx*4+2] = v.z; tile[rr][tx*4+3] = v.w;
  }
  __syncthreads();
  short8 s;
  #pragma unroll
  for (int j = 0; j < 8; ++j) s[j] = (short)f2bf(tile[tx*8+j][ty]);
  *(short8*)(oute + (size_t)(c0 + ty) * R + r0 + tx*8) = s;
}

// ---------------- Fused prep: W1 transpose (blocks [0,nT)) + dispatch (blocks [nT,..)) ----
// Both are independent preludes to GEMM1; fusing saves a launch and lets the two
// BW-bound block types co-schedule. Whole blocks take one branch (no divergence).
__global__ void prep1_kernel(const float* __restrict__ W1e, unsigned short* __restrict__ Wt,
                             const float* __restrict__ x, const int* __restrict__ slot_src,
                             const int* __restrict__ counts, unsigned short* __restrict__ Xd,
                             int e_base, int nexp, int nTransBlocks)
{
  __shared__ float tile[64][33];
  const int bidx = (int)blockIdx.x;
  if (bidx < nTransBlocks) {
    // W1 [C][DFF] -> Wt [DFF][C]; bx over DFF/32=128, by over C/64=16, bz expert
    const int bx = bidx & 127;          // DFF_/32
    const int by = (bidx >> 7) & 15;    // C_/64
    const int bz = bidx >> 11;          // 128*16 = 2048 blocks per expert
    const float* ine = W1e + (size_t)bz * C_ * DFF_;
    unsigned short* oute = Wt + (size_t)bz * C_ * DFF_;
    const int c0 = bx * 32, r0 = by * 64;
    const int tx = threadIdx.x & 7, ty = threadIdx.x >> 3;
    #pragma unroll
    for (int p = 0; p < 2; ++p) {
      const int rr = p*32 + ty;
      float4 v = *(const float4*)(ine + (size_t)(r0 + rr) * DFF_ + c0 + tx*4);
      tile[rr][tx*4+0] = v.x; tile[rr][tx*4+1] = v.y;
      tile[rr][tx*4+2] = v.z; tile[rr][tx*4+3] = v.w;
    }
    __syncthreads();
    short8 s;
    #pragma unroll
    for (int j = 0; j < 8; ++j) s[j] = (short)f2bf(tile[tx*8+j][ty]);
    *(short8*)(oute + (size_t)(c0 + ty) * C_ + r0 + tx*8) = s;
  } else {
    const int row = (bidx - nTransBlocks)*4 + ((int)threadIdx.x >> 6);
    const int lane = threadIdx.x & 63;
    const int total = nexp * B_ * CAP_;
    if (row >= total) return;
    int el = row / (B_*CAP_);
    int rem = row - el*(B_*CAP_);
    int b = rem / CAP_, slot = rem - b*CAP_;
    int eg = e_base + el;
    int cnt = counts[eg*B_ + b]; if (cnt > CAP_) cnt = CAP_;
    unsigned short* orow = Xd + (size_t)row * C_;
    if (slot < cnt) {
      int t = slot_src[((size_t)eg*B_ + b)*CAP_ + slot];
      const float4* xr = (const float4*)(x + ((size_t)b*T_ + t)*C_);
      #pragma unroll
      for (int i = 0; i < C_/256; ++i) {
        float4 v = xr[i*64 + lane];
        ushort4 o;
        o.x = f2bf(v.x); o.y = f2bf(v.y); o.z = f2bf(v.z); o.w = f2bf(v.w);
        ((ushort4*)orow)[i*64 + lane] = o;
      }
    } else {
      ushort4 z; z.x = z.y = z.z = z.w = 0;
      #pragma unroll
      for (int i = 0; i < C_/256; ++i) ((ushort4*)orow)[i*64 + lane] = z;
    }
  }
}

// ---------------- GEMM 256x256, BK=64, mod-5 half-ring, ONE barrier/tile ----------------
// A [e][M][Kfull] bf16 x BT [e][N][Kfull] bf16 (+bias if non-null, opt relu) -> Out bf16.
// 512 threads = 8 waves (2M x 4N), per-wave 128x64 (8x4 16x16 frags, kk=2 K-halves).
// LDS 160KB: per operand a 5-SLOT ring of K-HALF tiles (256 rows x 32 shorts = 16KB);
// half h lives in slot h%5. mod-5 makes every stage target a slot whose half was
// fully read in tile t-1 (all reads retire before the t-1 boundary barrier via
// each wave's P4 lgkmcnt(0)) -> NO mid-tile WAR barrier needed. One barrier/tile.
// Register pipeline: fragment ds_reads issued one quadrant ahead with counted
// lgkmcnt(4/8/4/0) so MFMA clusters run while next reads are in flight.
// Stages: P1 A(2t+3), P2 B(2t+3), P3 A(2t+4), P4 B(2t+4); boundary vmcnt(4)
// drains exactly halves 2t+2,2t+3 (= tile t+1); never 0 until t+2==nk.
// T2 swizzle (0-conflict, verified r10/r11): 16B-chunk ^= ((row>>1)&3) on BOTH
// staging source and ds_read offsets; LDS dest linear (rule #21).
template<int RELU>
__global__ __launch_bounds__(512) void gemm256_kernel(
    const unsigned short* __restrict__ A,
    const unsigned short* __restrict__ BT,
    const float* __restrict__ bias,
    unsigned short* __restrict__ Out0,
    unsigned short* __restrict__ Out1,
    int M, int N, int Kfull, int klen, int tilesPerSplit, int nwg)
{
  __shared__ __align__(16) unsigned short lds[81920]; // 160 KiB: A 5x8192, B 5x8192 shorts
  const int NT = N >> 8, MT = M >> 8;
  const int bid = blockIdx.x;
  const int wg = (bid & 7) * (nwg >> 3) + (bid >> 3);
  const int sp  = wg / tilesPerSplit;
  const int wgr = wg - sp * tilesPerSplit;
  const int e  = wgr / (MT*NT);
  const int r2 = wgr - e*(MT*NT);
  const int mt = r2 / NT, nt = r2 - mt*NT;
  const int k0 = sp * klen;
  const unsigned short* Ae = A + (size_t)e * M * Kfull;
  const unsigned short* Be = BT + (size_t)e * N * Kfull;
  const float* be = bias ? (bias + (size_t)e * N) : nullptr;
  unsigned short* Oe = (sp == 0 ? Out0 : Out1) + (size_t)e * M * N;
  const int m0 = mt*256, n0 = nt*256;

  const int tid = threadIdx.x, lane = tid & 63, w = tid >> 6;
  const int wr = w >> 2, wc = w & 3;   // 2 x 4 waves

  floatx4 acc[8][4];
  #pragma unroll
  for (int i = 0; i < 8; ++i)
    #pragma unroll
    for (int j = 0; j < 4; ++j) acc[i][j] = (floatx4){0.f, 0.f, 0.f, 0.f};

  // Staging: one K-half = 256 rows x 32 shorts = 1024 chunks of 16B; thread covers
  // chunks tid (rows 0-127) and 512+tid (rows 128-255; +128 = row bit 7, XOR same).
  const int r0s = tid >> 2;           // 0..127
  const int p0s = ((tid & 3) ^ ((r0s >> 1) & 3)) * 8;   // shorts
  const unsigned short* gA0 = Ae + (size_t)(m0 + r0s)*Kfull + k0 + p0s;
  const unsigned short* gA1 = gA0 + (size_t)128*Kfull;
  const unsigned short* gB0 = Be + (size_t)(n0 + r0s)*Kfull + k0 + p0s;
  const unsigned short* gB1 = gB0 + (size_t)128*Kfull;
  const int la0 = w*512, la1 = 4096 + w*512;   // wave-uniform LDS bases (shorts)

  // Fragment reads: fr = lane&15, kq = lane>>4; (row>>1)&3 == (fr>>1)&3.
  const int fr = lane & 15, kq = lane >> 4;
  const int kqs = ((kq ^ ((fr >> 1) & 3)) * 8);
  const int aBase = (wr*128 + fr)*32 + kqs;            // + slot*8192 + mf*512
  const int bBase = 40960 + (wc*64 + fr)*32 + kqs;     // + slot*8192 + nf*512

  const int nk = klen >> 6;   // BK=64 tiles

#define STAGE_A(koff, s) do { \
    GLOAD16(gA0 + (size_t)(koff), lds + (s)*8192 + la0); \
    GLOAD16(gA1 + (size_t)(koff), lds + (s)*8192 + la1); } while(0)
#define STAGE_B(koff, s) do { \
    GLOAD16(gB0 + (size_t)(koff), lds + 40960 + (s)*8192 + la0); \
    GLOAD16(gB1 + (size_t)(koff), lds + 40960 + (s)*8192 + la1); } while(0)

  // prologue: halves 0,1 (tile 0) + half 2 (tile 1 kk0): 12 loads/thread
  STAGE_A(0, 0); STAGE_B(0, 0);
  STAGE_A(32, 1); STAGE_B(32, 1);
  STAGE_A(64, 2); STAGE_B(64, 2);
  asm volatile("s_waitcnt vmcnt(4)" ::: "memory");   // halves 0,1 landed
  BARRIER();

  int s0 = 0;  // slot of half 2t (advances +2 mod 5)
  for (int t = 0; t < nk; ++t) {
    const int s1  = (s0 + 1 >= 5) ? s0 - 4 : s0 + 1;   // half 2t+1
    const int sp3 = (s0 + 3 >= 5) ? s0 - 2 : s0 + 3;   // half 2t+3
    const int sp4 = (s0 + 4 >= 5) ? s0 - 1 : s0 + 4;   // half 2t+4
    const size_t kOdd = (size_t)(t + 1)*64 + 32;       // half 2t+3 k-offset
    const size_t kEv  = (size_t)(t + 2)*64;            // half 2t+4 k-offset
    const unsigned short* sA0 = lds + s0*8192;
    const unsigned short* sA1 = lds + s1*8192;
    short8 rB0[4], rA0lo[4], rA0hi[4], rB1[4], rA1lo[4], rA1hi[4];

    // ---- P1: issue rB0+rA0lo (8) | rA0hi (4); stage A(2t+3); MFMA Q1 ----
    #pragma unroll
    for (int nf = 0; nf < 4; ++nf) rB0[nf] = *(const short8*)(sA0 + bBase + nf*512);
    #pragma unroll
    for (int mf = 0; mf < 4; ++mf) rA0lo[mf] = *(const short8*)(sA0 + aBase + mf*512);
    SCHEDB();
    #pragma unroll
    for (int mf = 0; mf < 4; ++mf) rA0hi[mf] = *(const short8*)(sA0 + aBase + (mf+4)*512);
    if (t + 1 < nk) STAGE_A(kOdd, sp3);
    SCHEDB();
    asm volatile("s_waitcnt lgkmcnt(4)" ::: "memory");  // rB0,rA0lo ready; rA0hi flying
    SCHEDB();
    __builtin_amdgcn_s_setprio(1);
    #pragma unroll
    for (int mf = 0; mf < 4; ++mf)
      #pragma unroll
      for (int nf = 0; nf < 4; ++nf)
        acc[mf][nf] = __builtin_amdgcn_mfma_f32_16x16x32_bf16(rA0lo[mf], rB0[nf], acc[mf][nf], 0, 0, 0);
    __builtin_amdgcn_s_setprio(0);
    SCHEDB();

    // ---- P2: issue rB1+rA1lo (8); stage B(2t+3); MFMA Q2 (no barrier: mod-5 WAR-safe) ----
    #pragma unroll
    for (int nf = 0; nf < 4; ++nf) rB1[nf] = *(const short8*)(sA1 + bBase + nf*512);
    #pragma unroll
    for (int mf = 0; mf < 4; ++mf) rA1lo[mf] = *(const short8*)(sA1 + aBase + mf*512);
    if (t + 1 < nk) STAGE_B(kOdd, sp3);
    SCHEDB();
    asm volatile("s_waitcnt lgkmcnt(8)" ::: "memory");  // rA0hi ready
    SCHEDB();
    __builtin_amdgcn_s_setprio(1);
    #pragma unroll
    for (int mf = 0; mf < 4; ++mf)
      #pragma unroll
      for (int nf = 0; nf < 4; ++nf)
        acc[mf+4][nf] = __builtin_amdgcn_mfma_f32_16x16x32_bf16(rA0hi[mf], rB0[nf], acc[mf+4][nf], 0, 0, 0);
    __builtin_amdgcn_s_setprio(0);
    SCHEDB();

    // ---- P3: issue rA1hi (4); stage A(2t+4); MFMA Q3 ----
    #pragma unroll
    for (int mf = 0; mf < 4; ++mf) rA1hi[mf] = *(const short8*)(sA1 + aBase + (mf+4)*512);
    if (t + 2 < nk) STAGE_A(kEv, sp4);
    SCHEDB();
    asm volatile("s_waitcnt lgkmcnt(4)" ::: "memory");  // rB1,rA1lo ready; rA1hi flying
    SCHEDB();
    __builtin_amdgcn_s_setprio(1);
    #pragma unroll
    for (int mf = 0; mf < 4; ++mf)
      #pragma unroll
      for (int nf = 0; nf < 4; ++nf)
        acc[mf][nf] = __builtin_amdgcn_mfma_f32_16x16x32_bf16(rA1lo[mf], rB1[nf], acc[mf][nf], 0, 0, 0);
    __builtin_amdgcn_s_setprio(0);
    SCHEDB();

    // ---- P4: stage B(2t+4); MFMA Q4; publish boundary ----
    if (t + 2 < nk) STAGE_B(kEv, sp4);
    SCHEDB();
    asm volatile("s_waitcnt lgkmcnt(0)" ::: "memory");  // rA1hi ready
    SCHEDB();
    __builtin_amdgcn_s_setprio(1);
    #pragma unroll
    for (int mf = 0; mf < 4; ++mf)
      #pragma unroll
      for (int nf = 0; nf < 4; ++nf)
        acc[mf+4][nf] = __builtin_amdgcn_mfma_f32_16x16x32_bf16(rA1hi[mf], rB1[nf], acc[mf+4][nf], 0, 0, 0);
    __builtin_amdgcn_s_setprio(0);
    SCHEDB();

    if (t + 1 < nk) {
      if (t + 2 < nk) asm volatile("s_waitcnt vmcnt(4)" ::: "memory");
      else            asm volatile("s_waitcnt vmcnt(0)" ::: "memory");
      BARRIER();   // tile t+1 (halves 2t+2, 2t+3) published
    }
    s0 += 2; if (s0 >= 5) s0 -= 5;
  }
#undef STAGE_A
#undef STAGE_B

  // epilogue: C/D layout col = lane&15, row = (lane>>4)*4 + reg
  const int col = lane & 15, rbase = (lane >> 4) * 4;
  #pragma unroll
  for (int mf = 0; mf < 8; ++mf) {
    const int gr0 = m0 + wr*128 + mf*16 + rbase;
    #pragma unroll
    for (int nf = 0; nf < 4; ++nf) {
      const int gc = n0 + wc*64 + nf*16 + col;
      const float bv = be ? be[gc] : 0.f;
      #pragma unroll
      for (int r = 0; r < 4; ++r) {
        float v = acc[mf][nf][r] + bv;
        if (RELU) v = fmaxf(v, 0.f);
        Oe[(size_t)(gr0 + r)*N + gc] = f2bf(v);
      }
    }
  }
}

// ---------------- Combine ----------------
__global__ void combine_kernel(const unsigned short* __restrict__ Y0,
                               const unsigned short* __restrict__ Y1,
                               const float* __restrict__ b2c,
                               const int* __restrict__ topk_e, const float* __restrict__ topk_p,
                               const int* __restrict__ pos_arr, float* __restrict__ out)
{
  int token = (int)((blockIdx.x * blockDim.x + threadIdx.x) >> 6);
  int lane = threadIdx.x & 63;
  if (token >= NTOK) return;
  int b = token / T_, t = token - b*T_;
  int s0 = b*S_ + t*2;
  float acc[16];
  #pragma unroll
  for (int i = 0; i < 16; ++i) acc[i] = 0.f;
  #pragma unroll
  for (int k = 0; k < 2; ++k) {
    int pos = pos_arr[s0 + k];
    if (pos < 0) continue;
    int e = topk_e[s0 + k];
    float p = topk_p[s0 + k];
    size_t rowoff = (((size_t)e*B_ + b)*CAP_ + pos) * C_;
    const unsigned short* yr0 = Y0 + rowoff;
    const unsigned short* yr1 = Y1 ? (Y1 + rowoff) : nullptr;
    const float* bb = b2c ? (b2c + (size_t)e * C_) : nullptr;
    #pragma unroll
    for (int i = 0; i < 4; ++i) {
      ushort4 v = ((const ushort4*)yr0)[i*64 + lane];
      float s0v = bf2f(v.x), s1v = bf2f(v.y), s2v = bf2f(v.z), s3v = bf2f(v.w);
      if (yr1) {
        ushort4 u = ((const ushort4*)yr1)[i*64 + lane];
        s0v += bf2f(u.x); s1v += bf2f(u.y); s2v += bf2f(u.z); s3v += bf2f(u.w);
      }
      if (bb) {
        float4 bv = ((const float4*)bb)[i*64 + lane];
        s0v += bv.x; s1v += bv.y; s2v += bv.z; s3v += bv.w;
      }
      acc[i*4+0] += p * s0v;
      acc[i*4+1] += p * s1v;
      acc[i*4+2] += p * s2v;
      acc[i*4+3] += p * s3v;
    }
  }
  float4* orow = (float4*)(out + (size_t)token * C_);
  #pragma unroll
  for (int i = 0; i < 4; ++i) {
    float4 o;
    o.x = acc[i*4+0]; o.y = acc[i*4+1]; o.z = acc[i*4+2]; o.w = acc[i*4+3];
    orow[i*64 + lane] = o;
  }
}

extern "C" void kernel_launch(void* const* d_in, const int* in_sizes, int n_in,
                              void* d_out, int out_size, void* d_ws, size_t ws_size,
                              hipStream_t stream)
{
  const float* x  = (const float*)d_in[0];
  const float* Wg = (const float*)d_in[1];
  const float* bg = (const float*)d_in[2];
  const float* W1 = (const float*)d_in[3];
  const float* b1 = (const float*)d_in[4];
  const float* W2 = (const float*)d_in[5];
  const float* b2 = (const float*)d_in[6];
  float* out = (float*)d_out;

  char* ws = (char*)d_ws;
  size_t off = 0;
  auto alloc = [&](size_t bytes) -> char* {
    char* p = ws + off;
    off = (off + bytes + 255) & ~(size_t)255;
    return p;
  };
  int*   topk_e  = (int*)  alloc((size_t)NTOK * K_ * 4);
  float* topk_p  = (float*)alloc((size_t)NTOK * K_ * 4);
  int*   pos_arr = (int*)  alloc((size_t)B_ * S_ * 4);
  int*   slot_src= (int*)  alloc((size_t)E_ * B_ * CAP_ * 4);
  int*   counts  = (int*)  alloc((size_t)E_ * B_ * 4);
  unsigned short* Ybuf = (unsigned short*)alloc((size_t)E_ * ROWS_PER_E * C_ * 2);
  size_t fixed = off;
  const size_t perE = (size_t)C_ * DFF_ * 2
                    + (size_t)ROWS_PER_E * C_ * 2
                    + (size_t)ROWS_PER_E * DFF_ * 2
                    + 3 * 256;
  int k = 8;
  while (k > 1 && fixed + (size_t)k * perE > ws_size) k >>= 1;
  unsigned short* Wt = (unsigned short*)alloc((size_t)k * C_ * DFF_ * 2);
  unsigned short* Xd = (unsigned short*)alloc((size_t)k * ROWS_PER_E * C_ * 2);
  unsigned short* Hb = (unsigned short*)alloc((size_t)k * ROWS_PER_E * DFF_ * 2);

  router_kernel<<<NTOK/4, 256, 0, stream>>>(x, Wg, bg, topk_e, topk_p);
  scan_kernel<<<B_, 256, 0, stream>>>(topk_e, pos_arr, slot_src, counts);

  const bool splitK2 = (k == 8);

  for (int eb = 0; eb < E_; eb += k) {
    // fused: W1 transpose + dispatch (independent preludes to GEMM1)
    {
      int nT = k * (DFF_/32) * (C_/64);              // 2048 per expert
      int nD = (k * ROWS_PER_E) / 4;
      prep1_kernel<<<nT + nD, 256, 0, stream>>>(
          W1 + (size_t)eb * C_ * DFF_, Wt, x, slot_src, counts, Xd, eb, k, nT);
    }
    // H = relu(Xd @ W1 + b1)
    {
      int tiles = k * (ROWS_PER_E/256) * (DFF_/256);
      gemm256_kernel<1><<<tiles, 512, 0, stream>>>(
          Xd, Wt, b1 + (size_t)eb * DFF_, Hb, Hb, ROWS_PER_E, DFF_, C_, C_, tiles, tiles);
    }
    transpose_conv_kernel<<<dim3(C_/32, DFF_/64, k), 256, 0, stream>>>(
        W2 + (size_t)eb * DFF_ * C_, Wt, DFF_, C_);
    // Y = H @ W2
    {
      int tiles = k * (ROWS_PER_E/256) * (C_/256);
      if (splitK2) {
        gemm256_kernel<0><<<2*tiles, 512, 0, stream>>>(
            Hb, Wt, nullptr, Ybuf, Xd, ROWS_PER_E, C_, DFF_, DFF_/2, tiles, 2*tiles);
      } else {
        gemm256_kernel<0><<<tiles, 512, 0, stream>>>(
            Hb, Wt, b2 + (size_t)eb * C_, Ybuf + (size_t)eb * ROWS_PER_E * C_,
            Ybuf + (size_t)eb * ROWS_PER_E * C_, ROWS_PER_E, C_, DFF_, DFF_, tiles, tiles);
      }
    }
  }

  combine_kernel<<<NTOK/4, 256, 0, stream>>>(
      Ybuf, splitK2 ? Xd : nullptr, splitK2 ? b2 : nullptr,
      topk_e, topk_p, pos_arr, out);
}